// Round 1
// baseline (13.413 us; speedup 1.0000x reference)
//
#include <hip/hip_runtime.h>
#include <math.h>

#define KS   7
#define PAD  3
#define TH   8                      // output rows per block
#define W128 128
#define HALO_H (TH + KS - 1)        // 14
#define HALO_W (W128 + KS - 1)      // 134

__global__ __launch_bounds__(256) void dilation_r2_kernel(
    const float* __restrict__ x,      // [4,32,128,128]
    const float* __restrict__ dm,     // [32,2,2]
    float* __restrict__ out)          // [4,32,128,128]
{
    __shared__ float ksm[KS * KS];
    __shared__ float sx[HALO_H][HALO_W];

    const int tid  = threadIdx.x;
    const int tile = blockIdx.x;   // 0..15  (h tile)
    const int c    = blockIdx.y;   // 0..31
    const int n    = blockIdx.z;   // 0..3
    const int h0   = tile * TH;

    // ---- per-channel 7x7 kernel table (49 threads) ----
    if (tid < KS * KS) {
        const int i = tid / KS, j = tid % KS;
        const float yi = (float)(i - PAD);
        const float yj = (float)(j - PAD);
        const float m00 = dm[c * 4 + 0], m01 = dm[c * 4 + 1];
        const float m10 = dm[c * 4 + 2], m11 = dm[c * 4 + 3];
        const float d0 = m00 * yi + m01 * yj;
        const float d1 = m10 * yi + m11 * yj;
        const float s  = d0 * d0 + d1 * d1;
        // p = 2a/(2a-1) = 13/3 ; const = (2a-1)/(2a)^p = 0.3/1.3^(13/3)
        const float pc = (float)(0.3 / pow(1.3, 13.0 / 3.0));
        ksm[tid] = pc * powf(s, (float)(13.0 / 6.0));
    }

    // ---- stage x tile (+halo, zero pad) into LDS ----
    const float* xc = x + ((size_t)(n * 32 + c)) * (W128 * W128);
    for (int idx = tid; idx < HALO_H * HALO_W; idx += 256) {
        const int r  = idx / HALO_W;
        const int cc = idx - r * HALO_W;
        const int gh = h0 + r - PAD;
        const int gw = cc - PAD;
        float v = 0.0f;
        if (gh >= 0 && gh < W128 && gw >= 0 && gw < W128)
            v = xc[gh * W128 + gw];
        sx[r][cc] = v;
    }
    __syncthreads();

    // ---- each thread: 4 consecutive output rows at one column ----
    const int w  = tid & (W128 - 1);
    const int hq = (tid >> 7) * 4;   // 0 or 4
    float acc0 = -INFINITY, acc1 = -INFINITY, acc2 = -INFINITY, acc3 = -INFINITY;

    #pragma unroll
    for (int j = 0; j < KS; ++j) {
        float col[TH / 2 + KS - 1];  // 10 rows feed 4 outputs x 7 taps
        #pragma unroll
        for (int r = 0; r < TH / 2 + KS - 1; ++r)
            col[r] = sx[hq + r][w + j];
        #pragma unroll
        for (int i = 0; i < KS; ++i) {
            const float k = ksm[i * KS + j];   // lane-uniform broadcast
            acc0 = fmaxf(acc0, col[i + 0] - k);
            acc1 = fmaxf(acc1, col[i + 1] - k);
            acc2 = fmaxf(acc2, col[i + 2] - k);
            acc3 = fmaxf(acc3, col[i + 3] - k);
        }
    }

    float* oc = out + ((size_t)(n * 32 + c)) * (W128 * W128) + (h0 + hq) * W128 + w;
    oc[0 * W128] = acc0;
    oc[1 * W128] = acc1;
    oc[2 * W128] = acc2;
    oc[3 * W128] = acc3;
}

extern "C" void kernel_launch(void* const* d_in, const int* in_sizes, int n_in,
                              void* d_out, int out_size, void* d_ws, size_t ws_size,
                              hipStream_t stream) {
    const float* x  = (const float*)d_in[0];   // [4,32,128,128] f32
    const float* dm = (const float*)d_in[1];   // [32,2,2] f32
    float* out = (float*)d_out;

    dim3 grid(W128 / TH, 32, 4);   // (16, 32, 4) = 2048 blocks
    dim3 block(256);
    dilation_r2_kernel<<<grid, block, 0, stream>>>(x, dm, out);
}

// Round 2
// 12.061 us; speedup vs baseline: 1.1121x; 1.1121x over previous
//
#include <hip/hip_runtime.h>
#include <math.h>

typedef float f4 __attribute__((ext_vector_type(4)));

#define KS     7
#define W      128
#define TILE_H 32
#define HALO_H (TILE_H + KS - 1)    // 38
#define STR    136                   // LDS row: 4 zero | 128 data | 4 zero
#define CHK    (STR / 4)             // 34 float4 chunks per row
#define NCHK   (HALO_H * CHK)        // 1292

__global__ __launch_bounds__(256) void dil_kernel(
    const float* __restrict__ x,      // [4,32,128,128]
    const float* __restrict__ dm,     // [32,2,2]
    float* __restrict__ out)          // [4,32,128,128]
{
    __shared__ __align__(16) float ksm[52];
    __shared__ __align__(16) float sx[HALO_H * STR];

    const int tid = threadIdx.x;
    const int c   = blockIdx.y;
    const int n   = blockIdx.z;
    const int h0  = blockIdx.x * TILE_H;

    // ---- per-channel 7x7 kernel, NEGATED, padded to 52 ----
    if (tid < 52) {
        float v = -1e30f;
        if (tid < 49) {
            const int i = tid / KS, j = tid % KS;
            const float yi = (float)(i - 3), yj = (float)(j - 3);
            const float m00 = dm[c*4+0], m01 = dm[c*4+1];
            const float m10 = dm[c*4+2], m11 = dm[c*4+3];
            const float d0 = m00*yi + m01*yj;
            const float d1 = m10*yi + m11*yj;
            const float s  = d0*d0 + d1*d1;
            const float pc = (float)(0.3 / pow(1.3, 13.0/3.0));
            v = -(pc * powf(s, (float)(13.0/6.0)));
        }
        ksm[tid] = v;
    }

    // ---- stage halo tile as aligned float4 chunks (zero pad built in) ----
    const float* xc = x + ((size_t)(n*32 + c)) * (W*W);
    #pragma unroll
    for (int it = 0; it < 6; ++it) {
        const int idx = tid + it*256;
        if (idx < NCHK) {
            const int r  = idx / CHK;
            const int m  = idx - r*CHK;
            const int gh = h0 + r - 3;
            f4 v = {0.f, 0.f, 0.f, 0.f};
            if (m >= 1 && m <= 32 && gh >= 0 && gh < W)
                v = *reinterpret_cast<const f4*>(xc + gh*W + (m-1)*4);
            *reinterpret_cast<f4*>(sx + idx*4) = v;
        }
    }
    __syncthreads();

    // ---- pull negated kernel into registers (13 x b128, static-indexed) ----
    f4 kr[13];
    #pragma unroll
    for (int q = 0; q < 13; ++q)
        kr[q] = *reinterpret_cast<const f4*>(ksm + q*4);
#define NK(i, j) kr[((i)*KS + (j)) >> 2][((i)*KS + (j)) & 3]

    const int w4 = (tid & 31) * 4;     // output col base
    const int hr = (tid >> 5) * 4;     // output row base within tile

    float acc[4][4];
    #pragma unroll
    for (int o = 0; o < 4; ++o)
        #pragma unroll
        for (int q = 0; q < 4; ++q)
            acc[o][q] = -INFINITY;

    #pragma unroll
    for (int r = 0; r < 10; ++r) {               // halo rows hr .. hr+9
        const float* row = sx + (hr + r) * STR + w4;
        const f4 a0 = *reinterpret_cast<const f4*>(row);
        const f4 a1 = *reinterpret_cast<const f4*>(row + 4);
        const f4 a2 = *reinterpret_cast<const f4*>(row + 8);
        float rw[12] = {a0[0],a0[1],a0[2],a0[3],
                        a1[0],a1[1],a1[2],a1[3],
                        a2[0],a2[1],a2[2],a2[3]};
        #pragma unroll
        for (int o = 0; o < 4; ++o) {
            const int i = r - o;                 // kernel row
            if (i < 0 || i >= KS) continue;      // folds at compile time
            #pragma unroll
            for (int q = 0; q < 4; ++q) {
                const float t0 = rw[q+1] + NK(i,0);
                const float t1 = rw[q+2] + NK(i,1);
                const float t2 = rw[q+3] + NK(i,2);
                const float t3 = rw[q+4] + NK(i,3);
                const float t4 = rw[q+5] + NK(i,4);
                const float t5 = rw[q+6] + NK(i,5);
                const float t6 = rw[q+7] + NK(i,6);
                const float m1 = fmaxf(fmaxf(t0, t1), t2);   // -> v_max3
                const float m2 = fmaxf(fmaxf(t3, t4), t5);   // -> v_max3
                acc[o][q] = fmaxf(fmaxf(m1, m2), fmaxf(t6, acc[o][q]));
            }
        }
    }

    // ---- coalesced float4 stores ----
    float* oc = out + ((size_t)(n*32 + c)) * (W*W) + (h0 + hr) * W + w4;
    #pragma unroll
    for (int o = 0; o < 4; ++o) {
        f4 v = {acc[o][0], acc[o][1], acc[o][2], acc[o][3]};
        *reinterpret_cast<f4*>(oc + o*W) = v;
    }
}

extern "C" void kernel_launch(void* const* d_in, const int* in_sizes, int n_in,
                              void* d_out, int out_size, void* d_ws, size_t ws_size,
                              hipStream_t stream) {
    const float* x  = (const float*)d_in[0];
    const float* dm = (const float*)d_in[1];
    float* out = (float*)d_out;

    dim3 grid(W / TILE_H, 32, 4);   // (4, 32, 4) = 512 blocks
    dim3 block(256);
    dil_kernel<<<grid, block, 0, stream>>>(x, dm, out);
}